// Round 1
// baseline (1420.827 us; speedup 1.0000x reference)
//
#include <hip/hip_runtime.h>
#include <math.h>

#define BB 8
#define HH 512
#define LSEQ 4096
#define NM 64
#define LOG2E 1.44269504088896340736f

// ws layout: per (h,n) 8 floats: zr zi Ar Ai wr wi growflag pad
// zr,zi = exp(w) for decaying modes (Re w <= 0), exp(-w)=zeta for growing modes.
// A = (Wc/Lambda) * conj(s)/(|s|^2 + 1e-7), s = geometric softmax denominator.
__global__ void dss_setup(const float* __restrict__ W, const float* __restrict__ log_step,
                          const float* __restrict__ Lre, const float* __restrict__ Lim,
                          float* __restrict__ ws) {
    int idx = blockIdx.x * blockDim.x + threadIdx.x;
    if (idx >= HH * NM) return;
    int h = idx >> 6, n = idx & 63;
    float step = expf(log_step[h]);
    float wr = step * Lre[n];
    float wi = step * Lim[n];
    bool grow = wr > 0.0f;                 // argmax(P.real) = L-1 iff Re(w)>0, else 0
    float mr  = grow ? -wr : wr;           // <= 0
    float phi = grow ? -wi : wi;
    // rho = exp(w) (decay) or exp(-w) (grow); |rho| <= 1
    float em = expf(mr);
    float zr = em * cosf(phi);
    float zi = em * sinf(phi);
    // s = sum_{m=0}^{L-1} rho^m = (1 - rho^L) / (1 - rho)   (valid in both cases)
    float magL = expf(mr * (float)LSEQ);   // underflows to 0 harmlessly
    float phiL = phi * (float)LSEQ;
    float rLr = magL * cosf(phiL);
    float rLi = magL * sinf(phiL);
    float dr = 1.0f - zr, di = -zi;
    float den = dr * dr + di * di;
    float sr, si;
    if (den < 1e-24f) { sr = (float)LSEQ; si = 0.0f; }  // rho -> 1 limit
    else {
        float nr = 1.0f - rLr, ni = -rLi;
        float inv = 1.0f / den;
        sr = (nr * dr + ni * di) * inv;
        si = (ni * dr - nr * di) * inv;
    }
    // sc = conj(s)/(|s|^2 + EPS)
    float s2 = sr * sr + si * si + 1e-7f;
    float is2 = 1.0f / s2;
    float scr =  sr * is2;
    float sci = -si * is2;
    // Wc / Lambda
    float Wre = W[idx * 2 + 0], Wim = W[idx * 2 + 1];
    float lr = Lre[n], li = Lim[n];
    float il2 = 1.0f / (lr * lr + li * li);
    float qr = (Wre * lr + Wim * li) * il2;
    float qi = (Wim * lr - Wre * li) * il2;
    float Ar = qr * scr - qi * sci;
    float Ai = qr * sci + qi * scr;
    float* o = ws + (size_t)idx * 8;
    o[0] = zr; o[1] = zi; o[2] = Ar; o[3] = Ai;
    o[4] = wr; o[5] = wi; o[6] = grow ? 1.0f : 0.0f; o[7] = 0.0f;
}

// One wave per (b,h) row, lane = mode. 4 waves (4 rows) per 256-thread block.
__global__ __launch_bounds__(256, 4) void dss_scan(const float* __restrict__ u,
                                                   const float* __restrict__ ws,
                                                   const float* __restrict__ D,
                                                   float* __restrict__ y) {
    int wave = threadIdx.x >> 6;
    int lane = threadIdx.x & 63;
    int bh = blockIdx.x * 4 + wave;        // b*H + h
    int h  = bh & (HH - 1);
    const float* p = ws + (size_t)(h * NM + lane) * 8;
    float zr = p[0], zi = p[1], Ar = p[2], Ai = p[3], wr = p[4], wi = p[5];
    bool grow = wr > 0.0f;
    float Dh = D[h];
    const float* ub = u + (size_t)bh * LSEQ;
    float*       yb = y + (size_t)bh * LSEQ;

    // decay state x
    float xr = 0.0f, xi = 0.0f;
    // grow state: hh = sum zeta^j u[j]; pzl = zeta^l; phA = A * cis(wi*(l-(L-1)))
    float hhr = 0.0f, hhi = 0.0f;
    float pzr = 1.0f, pzi = 0.0f;
    float s0, c0;
    sincosf(-wi * (float)LSEQ, &s0, &c0);  // init at l = -1: angle = -wi*L
    float phAr = Ar * c0 - Ai * s0;
    float phAi = Ar * s0 + Ai * c0;
    float cw = cosf(wi), sw = sinf(wi);
    float wrl2e = wr * LOG2E;

    for (int sc_ = 0; sc_ < LSEQ / 256; ++sc_) {       // 16 super-chunks of 256
        float4 u4 = ((const float4*)ub)[sc_ * 64 + lane];
        for (int q = 0; q < 4; ++q) {                   // 4 sub-chunks of 64
            float keep = 0.0f;
            #pragma unroll 4
            for (int i = 0; i < 16; ++i) {
                int src = q * 16 + i;
                float b0 = __shfl(u4.x, src, 64);
                float b1 = __shfl(u4.y, src, 64);
                float b2 = __shfl(u4.z, src, 64);
                float b3 = __shfl(u4.w, src, 64);
                float bb4[4] = {b0, b1, b2, b3};
                #pragma unroll
                for (int k = 0; k < 4; ++k) {
                    float uj = bb4[k];
                    int j = i * 4 + k;                  // position within sub-chunk
                    int l = ((sc_ * 4 + q) << 6) + j;   // global position
                    // ---- decay path: x = z*x + u; cd = Re(A*x)
                    float xin = fmaf(zr, xi, zi * xr);
                    float t0  = fmaf(zr, xr, uj);
                    float xrn = fmaf(-zi, xi, t0);
                    xr = xrn; xi = xin;
                    float cd = fmaf(Ar, xr, -(Ai * xi));
                    // ---- grow path: hh += zeta^l * u; contrib = Re(A*zeta^(L-1-l)*hh)
                    hhr = fmaf(pzr, uj, hhr);
                    hhi = fmaf(pzi, uj, hhi);
                    float prn = fmaf(zr, pzr, -(zi * pzi));
                    float pin = fmaf(zr, pzi, zi * pzr);
                    pzr = prn; pzi = pin;
                    float par = fmaf(cw, phAr, -(sw * phAi));
                    float pai = fmaf(cw, phAi, sw * phAr);
                    phAr = par; phAi = pai;
                    float qmag = exp2f(wrl2e * (float)(l - (LSEQ - 1)));
                    float tg = fmaf(phAr, hhr, -(phAi * hhi));
                    float contrib = grow ? (qmag * tg) : cd;
                    // ---- reduce over 64 modes
                    contrib += __shfl_xor(contrib, 1, 64);
                    contrib += __shfl_xor(contrib, 2, 64);
                    contrib += __shfl_xor(contrib, 4, 64);
                    contrib += __shfl_xor(contrib, 8, 64);
                    contrib += __shfl_xor(contrib, 16, 64);
                    contrib += __shfl_xor(contrib, 32, 64);
                    float tot = fmaf(Dh, uj, contrib);
                    keep = (lane == j) ? tot : keep;
                }
            }
            yb[((sc_ * 4 + q) << 6) + lane] = keep;
        }
    }
}

extern "C" void kernel_launch(void* const* d_in, const int* in_sizes, int n_in,
                              void* d_out, int out_size, void* d_ws, size_t ws_size,
                              hipStream_t stream) {
    const float* u   = (const float*)d_in[0];
    const float* W   = (const float*)d_in[1];
    const float* D   = (const float*)d_in[2];
    const float* ls  = (const float*)d_in[3];
    const float* lre = (const float*)d_in[4];
    const float* lim = (const float*)d_in[5];
    float* y  = (float*)d_out;
    float* ws = (float*)d_ws;   // needs H*N*8*4 = 1 MiB

    dss_setup<<<(HH * NM + 255) / 256, 256, 0, stream>>>(W, ls, lre, lim, ws);
    dss_scan<<<(BB * HH) / 4, 256, 0, stream>>>(u, ws, D, y);
}

// Round 2
// 1016.352 us; speedup vs baseline: 1.3980x; 1.3980x over previous
//
#include <hip/hip_runtime.h>
#include <math.h>

#define BB 8
#define HH 512
#define LSEQ 4096
#define NM 64
#define LOG2E 1.44269504088896340736f

// ws layout: per (h,n) 8 floats: zr zi Ar Ai wr wi growflag pad
__global__ void dss_setup(const float* __restrict__ W, const float* __restrict__ log_step,
                          const float* __restrict__ Lre, const float* __restrict__ Lim,
                          float* __restrict__ ws) {
    int idx = blockIdx.x * blockDim.x + threadIdx.x;
    if (idx >= HH * NM) return;
    int h = idx >> 6, n = idx & 63;
    float step = expf(log_step[h]);
    float wr = step * Lre[n];
    float wi = step * Lim[n];
    bool grow = wr > 0.0f;                 // argmax(P.real) = L-1 iff Re(w)>0, else 0
    float mr  = grow ? -wr : wr;           // <= 0
    float phi = grow ? -wi : wi;
    float em = expf(mr);
    float zr = em * cosf(phi);
    float zi = em * sinf(phi);
    // s = sum_{m=0}^{L-1} rho^m = (1 - rho^L) / (1 - rho)
    float magL = expf(mr * (float)LSEQ);   // underflows to 0 harmlessly
    float phiL = phi * (float)LSEQ;
    float rLr = magL * cosf(phiL);
    float rLi = magL * sinf(phiL);
    float dr = 1.0f - zr, di = -zi;
    float den = dr * dr + di * di;
    float sr, si;
    if (den < 1e-24f) { sr = (float)LSEQ; si = 0.0f; }
    else {
        float nr = 1.0f - rLr, ni = -rLi;
        float inv = 1.0f / den;
        sr = (nr * dr + ni * di) * inv;
        si = (ni * dr - nr * di) * inv;
    }
    float s2 = sr * sr + si * si + 1e-7f;
    float is2 = 1.0f / s2;
    float scr =  sr * is2;
    float sci = -si * is2;
    float Wre = W[idx * 2 + 0], Wim = W[idx * 2 + 1];
    float lr = Lre[n], li = Lim[n];
    float il2 = 1.0f / (lr * lr + li * li);
    float qr = (Wre * lr + Wim * li) * il2;
    float qi = (Wim * lr - Wre * li) * il2;
    float Ar = qr * scr - qi * sci;
    float Ai = qr * sci + qi * scr;
    float* o = ws + (size_t)idx * 8;
    o[0] = zr; o[1] = zi; o[2] = Ar; o[3] = Ai;
    o[4] = wr; o[5] = wi; o[6] = grow ? 1.0f : 0.0f; o[7] = 0.0f;
}

// One wave per (b,h) row; block = exactly one wave so that the row base
// pointer is blockIdx-derived => wave-uniform => u loads become s_load
// (SMEM pipe), eliminating all broadcast shuffles from the DS pipe.
__global__ __launch_bounds__(64, 4) void dss_scan(const float* __restrict__ u,
                                                  const float* __restrict__ ws,
                                                  const float* __restrict__ D,
                                                  float* __restrict__ y) {
    int lane = threadIdx.x;                // 0..63, = mode
    int bh = blockIdx.x;                   // b*H + h
    int h  = bh & (HH - 1);
    const float* p = ws + (size_t)(h * NM + lane) * 8;
    float zr = p[0], zi = p[1], Ar = p[2], Ai = p[3], wr = p[4], wi = p[5];
    bool grow = wr > 0.0f;
    float Dh = D[h];
    const float* ub = u + (size_t)bh * LSEQ;
    float*       yb = y + (size_t)bh * LSEQ;

    // decay state x
    float xr = 0.0f, xi = 0.0f;
    // grow state: hh = sum zeta^j u[j]; pz = zeta^l; phA = A * cis(wi*(l-(L-1)))
    float hhr = 0.0f, hhi = 0.0f;
    float pzr = 1.0f, pzi = 0.0f;
    float s0, c0;
    sincosf(-wi * (float)LSEQ, &s0, &c0);  // init at l = -1: angle = -wi*L
    float phAr = Ar * c0 - Ai * s0;
    float phAi = Ar * s0 + Ai * c0;
    float cw = cosf(wi), sw = sinf(wi);
    float wrl2e = wr * LOG2E;
    float negbase = -wrl2e * (float)(LSEQ - 1);
    float lf = 0.0f;                       // running float position counter
    int srcLane = (lane & 3) << 4;         // gather source for final placement

    for (int c = 0; c < LSEQ / 64; ++c) {  // 64 chunks of 64 positions
        float umy = ub[c * 64 + lane];     // per-lane vector load (coalesced)
        float dmy = Dh * umy;
        float keep = 0.0f;
        for (int i = 0; i < 16; ++i) {
            // wave-uniform address -> s_load_dwordx4, no DS traffic
            float4 uu = *(const float4*)(ub + c * 64 + i * 4);
            float us[4] = {uu.x, uu.y, uu.z, uu.w};
            float cc[4];
            #pragma unroll
            for (int k = 0; k < 4; ++k) {
                float uj = us[k];
                // ---- decay path: x = z*x + u; cd = Re(A*x)
                float xin = fmaf(zr, xi, zi * xr);
                float t0  = fmaf(zr, xr, uj);
                float xrn = fmaf(-zi, xi, t0);
                xr = xrn; xi = xin;
                float cd = fmaf(Ar, xr, -(Ai * xi));
                // ---- grow path: hh += zeta^l * u; contrib = qmag * Re(phA*hh)
                hhr = fmaf(pzr, uj, hhr);
                hhi = fmaf(pzi, uj, hhi);
                float prn = fmaf(zr, pzr, -(zi * pzi));
                float pin = fmaf(zr, pzi, zi * pzr);
                pzr = prn; pzi = pin;
                float par = fmaf(cw, phAr, -(sw * phAi));
                float pai = fmaf(cw, phAi, sw * phAr);
                phAr = par; phAi = pai;
                float qarg = fmaf(wrl2e, lf, negbase);
                lf += 1.0f;
                float qmag = exp2f(qarg);
                float tg = fmaf(phAr, hhr, -(phAi * hhi));
                cc[k] = grow ? (qmag * tg) : cd;
            }
            // ---- batched 4-position reduction over 64 modes: 8 shuffles total
            float a = ((lane & 32) ? cc[2] : cc[0]) +
                      __shfl_xor(((lane & 32) ? cc[0] : cc[2]), 32, 64);
            float b = ((lane & 32) ? cc[3] : cc[1]) +
                      __shfl_xor(((lane & 32) ? cc[1] : cc[3]), 32, 64);
            float acc = ((lane & 16) ? b : a) +
                        __shfl_xor(((lane & 16) ? a : b), 16, 64);
            acc += __shfl_xor(acc, 8, 64);
            acc += __shfl_xor(acc, 4, 64);
            acc += __shfl_xor(acc, 2, 64);
            acc += __shfl_xor(acc, 1, 64);
            // group g=lane>>4 holds sum for position i*4+g; route to lane i*4+g
            float res = __shfl(acc, srcLane, 64);
            keep = ((lane >> 2) == i) ? (res + dmy) : keep;
        }
        yb[c * 64 + lane] = keep;
    }
}

extern "C" void kernel_launch(void* const* d_in, const int* in_sizes, int n_in,
                              void* d_out, int out_size, void* d_ws, size_t ws_size,
                              hipStream_t stream) {
    const float* u   = (const float*)d_in[0];
    const float* W   = (const float*)d_in[1];
    const float* D   = (const float*)d_in[2];
    const float* ls  = (const float*)d_in[3];
    const float* lre = (const float*)d_in[4];
    const float* lim = (const float*)d_in[5];
    float* y  = (float*)d_out;
    float* ws = (float*)d_ws;   // needs H*N*8*4 = 1 MiB

    dss_setup<<<(HH * NM + 255) / 256, 256, 0, stream>>>(W, ls, lre, lim, ws);
    dss_scan<<<BB * HH, 64, 0, stream>>>(u, ws, D, y);
}

// Round 3
// 436.246 us; speedup vs baseline: 3.2569x; 2.3298x over previous
//
#include <hip/hip_runtime.h>
#include <math.h>

#define BB 8
#define HH 512
#define LSEQ 4096
#define NM 64
#define TT 16
#define NCH (LSEQ / TT)
#define L2E 1.44269504088896340736f
#define INV2PI 0.15915494309189535f
#define TWOPI 6.283185307179586f

// ws layout: per (h,n) 8 floats: zr zi Ar Ai wr wi grow khead
// slot 7 (pad) holds K-head: K[h,d] lives at ws[((h*64)+d)*8+7] for d<16.
__global__ void dss_setup(const float* __restrict__ W, const float* __restrict__ log_step,
                          const float* __restrict__ Lre, const float* __restrict__ Lim,
                          float* __restrict__ ws) {
    int idx = blockIdx.x * blockDim.x + threadIdx.x;
    if (idx >= HH * NM) return;
    int h = idx >> 6, n = idx & 63;
    float step = expf(log_step[h]);
    float wr = step * Lre[n];
    float wi = step * Lim[n];
    bool grow = wr > 0.0f;                 // argmax(P.real) = L-1 iff Re(w)>0, else 0
    float mr  = grow ? -wr : wr;           // <= 0
    float phi = grow ? -wi : wi;
    float em = expf(mr);
    float zr = em * cosf(phi);             // rho = e^w (decay) or zeta = e^-w (grow)
    float zi = em * sinf(phi);
    // s = sum_{m=0}^{L-1} rho^m = (1 - rho^L) / (1 - rho)
    float magL = expf(mr * (float)LSEQ);
    float phiL = phi * (float)LSEQ;
    float rLr = magL * cosf(phiL);
    float rLi = magL * sinf(phiL);
    float dr = 1.0f - zr, di = -zi;
    float den = dr * dr + di * di;
    float sr, si;
    if (den < 1e-24f) { sr = (float)LSEQ; si = 0.0f; }
    else {
        float nr = 1.0f - rLr, ni = -rLi;
        float inv = 1.0f / den;
        sr = (nr * dr + ni * di) * inv;
        si = (ni * dr - nr * di) * inv;
    }
    float s2 = sr * sr + si * si + 1e-7f;
    float is2 = 1.0f / s2;
    float scr =  sr * is2;
    float sci = -si * is2;
    float Wre = W[idx * 2 + 0], Wim = W[idx * 2 + 1];
    float lr = Lre[n], li = Lim[n];
    float il2 = 1.0f / (lr * lr + li * li);
    float qr = (Wre * lr + Wim * li) * il2;
    float qi = (Wim * lr - Wre * li) * il2;
    float Ar = qr * scr - qi * sci;
    float Ai = qr * sci + qi * scr;
    float* o = ws + (size_t)idx * 8;
    o[0] = zr; o[1] = zi; o[2] = Ar; o[3] = Ai;
    o[4] = wr; o[5] = wi; o[6] = grow ? 1.0f : 0.0f; o[7] = 0.0f;
}

// K-head: K[h,d] = D[h]*(d==0) + sum_n Re(A_n * rho_n-power), d = 0..15
__global__ void dss_khead(const float* __restrict__ D, float* __restrict__ ws) {
    int h = blockIdx.x;
    int lane = threadIdx.x;                // = mode
    const float* o = ws + (size_t)(h * NM + lane) * 8;
    float zr = o[0], zi = o[1], Ar = o[2], Ai = o[3], wr = o[4], wi = o[5];
    bool grow = wr > 0.0f;
    float pr = 1.0f, pi = 0.0f;            // z^d for decay path
    float kv = 0.0f;
    for (int d = 0; d < TT; ++d) {
        float contrib;
        if (grow) {
            // Re(A * zeta^(L-1-d)), zeta = e^-w
            float ex = (float)(LSEQ - 1 - d);
            float mag = exp2f(-wr * L2E * ex);
            float rev = -wi * INV2PI * ex;
            rev -= floorf(rev);
            float th = rev * TWOPI;
            float cr = mag * __cosf(th);
            float ci = mag * __sinf(th);
            contrib = Ar * cr - Ai * ci;
        } else {
            contrib = Ar * pr - Ai * pi;   // Re(A z^d)
        }
        // advance decay power
        float npr = pr * zr - pi * zi;
        float npi = pr * zi + pi * zr;
        pr = npr; pi = npi;
        // full-wave sum
        float tot = contrib;
        tot += __shfl_xor(tot, 1, 64);
        tot += __shfl_xor(tot, 2, 64);
        tot += __shfl_xor(tot, 4, 64);
        tot += __shfl_xor(tot, 8, 64);
        tot += __shfl_xor(tot, 16, 64);
        tot += __shfl_xor(tot, 32, 64);
        kv = (lane == d) ? tot : kv;
    }
    if (lane < TT) {
        float add = (lane == 0) ? D[h] : 0.0f;
        ws[(size_t)(h * NM + lane) * 8 + 7] = kv + add;
    }
}

// One wave per (b,h) row. Lane = mode for cross-chunk machinery.
// Chunked (T=16) state-passing: per chunk, y[t] = Re(B_t*gamma*state) + FIR + ...
__global__ __launch_bounds__(64, 4) void dss_scan(const float* __restrict__ u,
                                                  const float* __restrict__ ws,
                                                  float* __restrict__ y) {
    int lane = threadIdx.x;
    int bh = blockIdx.x;                   // b*H + h
    int h  = bh & (HH - 1);
    const float* p = ws + (size_t)(h * NM + lane) * 8;
    float zr = p[0], zi = p[1], Ar = p[2], Ai = p[3], wr = p[4], wi = p[5];
    bool grow = wr > 0.0f;
    const float* ub = u + (size_t)bh * LSEQ;
    float*       yb = y + (size_t)bh * LSEQ;

    // per-lane FIR taps: position-in-chunk t = lane&15; khp[s] = Khead[t-s] (0 if s>t)
    int t_ = lane & 15;
    float khp[TT];
    #pragma unroll
    for (int s = 0; s < TT; ++s)
        khp[s] = (s <= t_) ? ws[(size_t)(h * NM + (t_ - s)) * 8 + 7] : 0.0f;

    // loop-invariant per-mode constants
    float csr[TT], csi[TT], Br[TT], Bi[TT], alr, ali, gw2, gwrev;
    if (grow) {
        csr[0] = 1.0f; csi[0] = 0.0f;      // cs[s] = zeta^s
        #pragma unroll
        for (int s = 1; s < TT; ++s) {
            csr[s] = csr[s-1]*zr - csi[s-1]*zi;
            csi[s] = csr[s-1]*zi + csi[s-1]*zr;
        }
        Br[TT-1] = Ar; Bi[TT-1] = Ai;      // B[t] = A * zeta^(15-t)
        #pragma unroll
        for (int t = TT-2; t >= 0; --t) {
            Br[t] = Br[t+1]*zr - Bi[t+1]*zi;
            Bi[t] = Br[t+1]*zi + Bi[t+1]*zr;
        }
        alr = 1.0f; ali = 0.0f;
        gw2 = wr * L2E; gwrev = wi * INV2PI;
    } else {
        csr[TT-1] = 1.0f; csi[TT-1] = 0.0f; // cs[s] = z^(15-s)
        #pragma unroll
        for (int s = TT-2; s >= 0; --s) {
            csr[s] = csr[s+1]*zr - csi[s+1]*zi;
            csi[s] = csr[s+1]*zi + csi[s+1]*zr;
        }
        Br[0] = Ar*zr - Ai*zi;              // B[t] = A * z^(t+1)
        Bi[0] = Ar*zi + Ai*zr;
        #pragma unroll
        for (int t = 1; t < TT; ++t) {
            Br[t] = Br[t-1]*zr - Bi[t-1]*zi;
            Bi[t] = Br[t-1]*zi + Bi[t-1]*zr;
        }
        alr = csr[0]*zr - csi[0]*zi;        // z^16
        ali = csr[0]*zi + csi[0]*zr;
        gw2 = 0.0f; gwrev = 0.0f;
    }

    float str = 0.0f, sti = 0.0f;           // state: x[l0-1] (decay) / h[l0-1] (grow)
    float keep = 0.0f;
    int srcLane = t_ << 2;
    int myc = lane >> 4;

    for (int c = 0; c < NCH; ++c) {
        int l0 = c * TT;
        // wave-uniform u loads -> scalar pipe
        float4 q0 = *(const float4*)(ub + l0);
        float4 q1 = *(const float4*)(ub + l0 + 4);
        float4 q2 = *(const float4*)(ub + l0 + 8);
        float4 q3 = *(const float4*)(ub + l0 + 12);
        float us[TT] = {q0.x,q0.y,q0.z,q0.w, q1.x,q1.y,q1.z,q1.w,
                        q2.x,q2.y,q2.z,q2.w, q3.x,q3.y,q3.z,q3.w};
        // per-chunk scalars: gamma = e^{w(l0+15-(L-1))}, beta = zeta^{l0} (grow); (1,0) for decay
        float eg = (float)(l0 - (LSEQ - TT));
        float eb = (float)l0;
        float gmag = exp2f(gw2 * eg);
        float grv = gwrev * eg; grv -= floorf(grv);
        float gth = grv * TWOPI;
        float gcr = gmag * __cosf(gth);
        float gci = gmag * __sinf(gth);
        float bmag = exp2f(-gw2 * eb);
        float brv = -gwrev * eb; brv -= floorf(brv);
        float bth = brv * TWOPI;
        float ber = bmag * __cosf(bth);
        float bei = bmag * __sinf(bth);
        // g = gamma (.) state
        float ggr = gcr * str - gci * sti;
        float ggi = gcr * sti + gci * str;
        // partials (fused with butterfly step 1), fir, acc
        float fir = 0.0f, accr = 0.0f, acci = 0.0f;
        float v8[8];
        #pragma unroll
        for (int k = 0; k < 8; ++k) {
            float p0 = Br[k]   * ggr - Bi[k]   * ggi;   // position k
            float p1 = Br[k+8] * ggr - Bi[k+8] * ggi;   // position k+8
            fir  = fmaf(khp[k],   us[k],   fir);
            fir  = fmaf(khp[k+8], us[k+8], fir);
            accr = fmaf(csr[k],   us[k],   accr);
            acci = fmaf(csi[k],   us[k],   acci);
            accr = fmaf(csr[k+8], us[k+8], accr);
            acci = fmaf(csi[k+8], us[k+8], acci);
            float snd = (lane & 32) ? p0 : p1;
            float kp  = (lane & 32) ? p1 : p0;
            v8[k] = kp + __shfl_xor(snd, 32, 64);
        }
        // state = alpha(.)state + beta(.)acc
        float t1r = alr * str - ali * sti;
        float t1i = alr * sti + ali * str;
        float t2r = ber * accr - bei * acci;
        float t2i = ber * acci + bei * accr;
        str = t1r + t2r; sti = t1i + t2i;
        // butterfly steps 2-4 (multiplexed), then 2 plain steps
        float v4[4];
        #pragma unroll
        for (int k = 0; k < 4; ++k) {
            float snd = (lane & 16) ? v8[k] : v8[k+4];
            float kp  = (lane & 16) ? v8[k+4] : v8[k];
            v4[k] = kp + __shfl_xor(snd, 16, 64);
        }
        float v2[2];
        #pragma unroll
        for (int k = 0; k < 2; ++k) {
            float snd = (lane & 8) ? v4[k] : v4[k+2];
            float kp  = (lane & 8) ? v4[k+2] : v4[k];
            v2[k] = kp + __shfl_xor(snd, 8, 64);
        }
        float snd = (lane & 4) ? v2[0] : v2[1];
        float kp  = (lane & 4) ? v2[1] : v2[0];
        float v1 = kp + __shfl_xor(snd, 4, 64);
        v1 += __shfl_xor(v1, 2, 64);
        v1 += __shfl_xor(v1, 1, 64);        // lane holds sum for position (lane>>2)&15
        float routed = __shfl(v1, srcLane, 64);
        keep = (myc == (c & 3)) ? (routed + fir) : keep;
        if ((c & 3) == 3)
            yb[(c >> 2) * 64 + lane] = keep;
    }
}

extern "C" void kernel_launch(void* const* d_in, const int* in_sizes, int n_in,
                              void* d_out, int out_size, void* d_ws, size_t ws_size,
                              hipStream_t stream) {
    const float* u   = (const float*)d_in[0];
    const float* W   = (const float*)d_in[1];
    const float* D   = (const float*)d_in[2];
    const float* ls  = (const float*)d_in[3];
    const float* lre = (const float*)d_in[4];
    const float* lim = (const float*)d_in[5];
    float* y  = (float*)d_out;
    float* ws = (float*)d_ws;   // needs H*N*8*4 = 1 MiB

    dss_setup<<<(HH * NM + 255) / 256, 256, 0, stream>>>(W, ls, lre, lim, ws);
    dss_khead<<<HH, 64, 0, stream>>>(D, ws);
    dss_scan<<<BB * HH, 64, 0, stream>>>(u, ws, y);
}

// Round 4
// 230.146 us; speedup vs baseline: 6.1736x; 1.8955x over previous
//
#include <hip/hip_runtime.h>
#include <math.h>

#define BB 8
#define HH 512
#define LSEQ 4096
#define NM 64
#define CC 64
#define NCH (LSEQ / CC)
#define L2E 1.44269504088896340736f
#define INV2PI 0.15915494309189535f
#define TWOPI 6.283185307179586f

typedef __attribute__((ext_vector_type(8))) short short8;
typedef __attribute__((ext_vector_type(4))) float floatx4;

__device__ inline unsigned short f2bf(float x) {
    unsigned int u = __float_as_uint(x);
    unsigned int r = u + 0x7FFFu + ((u >> 16) & 1u);
    return (unsigned short)(r >> 16);
}

// rho^e where rho has log-magnitude m2 (base-2 per unit e) and angle av (revs per unit e)
__device__ inline void cpow(float m2, float av, float e, float& cr, float& ci) {
    float mag = exp2f(m2 * e);
    float rev = av * e; rev -= floorf(rev);
    float s, c;
    __sincosf(rev * TWOPI, &s, &c);
    cr = mag * c; ci = mag * s;
}

// ws layout per (h,n), 8 floats: zr zi Ar Ai wr wi grow ktap
__global__ void dss_setup(const float* __restrict__ W, const float* __restrict__ log_step,
                          const float* __restrict__ Lre, const float* __restrict__ Lim,
                          float* __restrict__ ws) {
    int idx = blockIdx.x * blockDim.x + threadIdx.x;
    if (idx >= HH * NM) return;
    int h = idx >> 6, n = idx & 63;
    float step = expf(log_step[h]);
    float wr = step * Lre[n];
    float wi = step * Lim[n];
    bool grow = wr > 0.0f;
    float mr  = grow ? -wr : wr;
    float phi = grow ? -wi : wi;
    float em = expf(mr);
    float zr = em * cosf(phi);             // rho = e^w (decay) or zeta = e^-w (grow)
    float zi = em * sinf(phi);
    float magL = expf(mr * (float)LSEQ);
    float phiL = phi * (float)LSEQ;
    float rLr = magL * cosf(phiL);
    float rLi = magL * sinf(phiL);
    float dr = 1.0f - zr, di = -zi;
    float den = dr * dr + di * di;
    float sr, si;
    if (den < 1e-24f) { sr = (float)LSEQ; si = 0.0f; }
    else {
        float nr = 1.0f - rLr, ni = -rLi;
        float inv = 1.0f / den;
        sr = (nr * dr + ni * di) * inv;
        si = (ni * dr - nr * di) * inv;
    }
    float s2 = sr * sr + si * si + 1e-7f;
    float is2 = 1.0f / s2;
    float scr =  sr * is2;
    float sci = -si * is2;
    float Wre = W[idx * 2 + 0], Wim = W[idx * 2 + 1];
    float lr = Lre[n], li = Lim[n];
    float il2 = 1.0f / (lr * lr + li * li);
    float qr = (Wre * lr + Wim * li) * il2;
    float qi = (Wim * lr - Wre * li) * il2;
    float Ar = qr * scr - qi * sci;
    float Ai = qr * sci + qi * scr;
    float* o = ws + (size_t)idx * 8;
    o[0] = zr; o[1] = zi; o[2] = Ar; o[3] = Ai;
    o[4] = wr; o[5] = wi; o[6] = grow ? 1.0f : 0.0f; o[7] = 0.0f;
}

// K taps for lags 0..63 per h (decay: Re(A z^d); grow: Re(A zeta^(L-1-d))); +D at lag 0
__global__ void dss_khead(const float* __restrict__ D, float* __restrict__ ws) {
    int h = blockIdx.x;
    int lane = threadIdx.x;
    const float* o = ws + (size_t)(h * NM + lane) * 8;
    float zr = o[0], zi = o[1], Ar = o[2], Ai = o[3], wr = o[4], wi = o[5];
    bool grow = wr > 0.0f;
    float pr = 1.0f, pi = 0.0f;
    float kv = 0.0f;
    for (int d = 0; d < CC; ++d) {
        float contrib;
        if (grow) {
            float cr, ci;
            cpow(-wr * L2E, -wi * INV2PI, (float)(LSEQ - 1 - d), cr, ci);
            contrib = Ar * cr - Ai * ci;
        } else {
            contrib = Ar * pr - Ai * pi;
        }
        float npr = pr * zr - pi * zi;
        float npi = pr * zi + pi * zr;
        pr = npr; pi = npi;
        float tot = contrib;
        tot += __shfl_xor(tot, 1, 64);
        tot += __shfl_xor(tot, 2, 64);
        tot += __shfl_xor(tot, 4, 64);
        tot += __shfl_xor(tot, 8, 64);
        tot += __shfl_xor(tot, 16, 64);
        tot += __shfl_xor(tot, 32, 64);
        kv = (lane == d) ? tot : kv;
    }
    float add = (lane == 0) ? D[h] : 0.0f;
    ws[(size_t)(h * NM + lane) * 8 + 7] = kv + add;
}

// One workgroup (4 waves) per (b,h) row.
__global__ __launch_bounds__(256) void dss_main(const float* __restrict__ u,
                                                const float* __restrict__ ws,
                                                float* __restrict__ y) {
    __shared__ __align__(16) short GT[64 * 200];   // [c][k]: k 0..127 = g re/im, 128..191 = u (bf16)
    __shared__ __align__(16) float ACCY[128 * 66]; // phase A out [m][c] stride 66; later Y [t][c] stride 67
    __shared__ float KTAP[64];

    int tid = threadIdx.x;
    int wv = tid >> 6, lane = tid & 63;
    int mrow = lane & 15;
    int quad = lane >> 4;
    int bh = blockIdx.x;
    int h = bh & (HH - 1);
    const float* ub = u + (size_t)bh * LSEQ;
    float* yb = y + (size_t)bh * LSEQ;

    // ---- stage u -> GT[c][128+s] as bf16 ----
    #pragma unroll
    for (int i = 0; i < 4; ++i) {
        int q = i * 256 + tid;
        float4 v = ((const float4*)ub)[q];
        int c = q >> 4;
        int s = (q & 15) * 4;
        ushort4 h4;
        h4.x = f2bf(v.x); h4.y = f2bf(v.y); h4.z = f2bf(v.z); h4.w = f2bf(v.w);
        *(ushort4*)&GT[c * 200 + 128 + s] = h4;
    }
    if (tid < 64) KTAP[tid] = ws[(size_t)(h * NM + tid) * 8 + 7];

    // ---- phase-A A-fragments (regs): WA[m=n][s]=Re(cs), WA[64+n][s]=Im(cs)
    // cs = z^(63-s) (decay) / zeta^s (grow); wave wv owns modes 16*wv..16*wv+15
    int nA = 16 * wv + mrow;
    const float* pA = ws + (size_t)(h * NM + nA) * 8;
    float zrA = pA[0], ziA = pA[1], wrA = pA[4], wiA = pA[5];
    bool growA = wrA > 0.0f;
    float m2A = (growA ? -wrA : wrA) * L2E;
    float avA = (growA ? -wiA : wiA) * INV2PI;
    short8 aRe[2], aIm[2];
    #pragma unroll
    for (int ks = 0; ks < 2; ++ks) {
        int s0 = ks * 32 + quad * 8;
        float cr[8], ci[8];
        if (growA) {
            cpow(m2A, avA, (float)s0, cr[0], ci[0]);
            #pragma unroll
            for (int j = 1; j < 8; ++j) {
                cr[j] = cr[j-1]*zrA - ci[j-1]*ziA;
                ci[j] = cr[j-1]*ziA + ci[j-1]*zrA;
            }
        } else {
            cpow(m2A, avA, (float)(56 - s0), cr[7], ci[7]);
            #pragma unroll
            for (int j = 6; j >= 0; --j) {
                cr[j] = cr[j+1]*zrA - ci[j+1]*ziA;
                ci[j] = cr[j+1]*ziA + ci[j+1]*zrA;
            }
        }
        #pragma unroll
        for (int j = 0; j < 8; ++j) {
            aRe[ks][j] = (short)f2bf(cr[j]);
            aIm[ks][j] = (short)f2bf(ci[j]);
        }
    }

    __syncthreads();

    // ---- phase A: ACC[128][64] = WA(128x64) * U(64x64) ----
    floatx4 accR[4], accI[4];
    #pragma unroll
    for (int nt = 0; nt < 4; ++nt) {
        accR[nt] = (floatx4){0.f,0.f,0.f,0.f};
        accI[nt] = (floatx4){0.f,0.f,0.f,0.f};
    }
    #pragma unroll
    for (int nt = 0; nt < 4; ++nt)
        #pragma unroll
        for (int ks = 0; ks < 2; ++ks) {
            short8 bfr = *(const short8*)&GT[(nt*16 + mrow) * 200 + 128 + ks*32 + quad*8];
            accR[nt] = __builtin_amdgcn_mfma_f32_16x16x32_bf16(aRe[ks], bfr, accR[nt], 0, 0, 0);
            accI[nt] = __builtin_amdgcn_mfma_f32_16x16x32_bf16(aIm[ks], bfr, accI[nt], 0, 0, 0);
        }
    #pragma unroll
    for (int nt = 0; nt < 4; ++nt)
        #pragma unroll
        for (int r = 0; r < 4; ++r) {
            int m = 16*wv + quad*4 + r;
            int col = nt*16 + mrow;
            ACCY[m * 66 + col] = accR[nt][r];
            ACCY[(64 + m) * 66 + col] = accI[nt][r];
        }

    __syncthreads();

    // ---- phase-C A-fragments: WC[t][n]=Re(B), [64+n]=-Im(B), [128+s]=Ktap[t-s]
    // B = A z^(t+1) (decay) / A zeta^(63-t) (grow); wave wv owns t-tile wv
    int trow = 16 * wv + mrow;
    short8 cf[6];
    #pragma unroll
    for (int g2 = 0; g2 < 2; ++g2)
        #pragma unroll
        for (int j = 0; j < 8; ++j) {
            int n = g2*32 + quad*8 + j;
            const float* pc = ws + (size_t)(h * NM + n) * 8;
            float Ar = pc[2], Ai = pc[3], wr = pc[4], wi = pc[5];
            bool grow = wr > 0.0f;
            float e = grow ? (float)(63 - trow) : (float)(trow + 1);
            float m2 = (grow ? -wr : wr) * L2E;
            float av = (grow ? -wi : wi) * INV2PI;
            float pr_, pi_;
            cpow(m2, av, e, pr_, pi_);
            float Br = Ar*pr_ - Ai*pi_;
            float Bi = Ar*pi_ + Ai*pr_;
            cf[g2][j]   = (short)f2bf(Br);
            cf[2+g2][j] = (short)f2bf(-Bi);
        }
    #pragma unroll
    for (int g2 = 0; g2 < 2; ++g2)
        #pragma unroll
        for (int j = 0; j < 8; ++j) {
            int s = g2*32 + quad*8 + j;
            float v = (s <= trow) ? KTAP[trow - s] : 0.0f;
            cf[4+g2][j] = (short)f2bf(v);
        }

    // ---- scan over 64 chunks (wave 0, lane = mode), fp32 ----
    if (wv == 0) {
        int n = lane;
        const float* ps = ws + (size_t)(h * NM + n) * 8;
        float zr = ps[0], zi = ps[1], wr = ps[4], wi = ps[5];
        bool grow = wr > 0.0f;
        float z64r = zr, z64i = zi;         // z^64 by 6 squarings (|z|<=1, underflow safe)
        #pragma unroll
        for (int k = 0; k < 6; ++k) {
            float tr = z64r*z64r - z64i*z64i;
            z64i = 2.0f*z64r*z64i;
            z64r = tr;
        }
        float alr = grow ? 1.0f : z64r, ali = grow ? 0.0f : z64i;
        float tur = grow ? z64r : 1.0f, tui = grow ? z64i : 0.0f;
        float gma = grow ? (-wr * L2E * (float)(LSEQ - CC)) : 0.0f;
        float gmd = grow ? (wr * L2E * (float)CC) : 0.0f;
        float rev0 = grow ? (-wi * INV2PI * (float)(LSEQ - CC)) : 0.0f;
        rev0 -= floorf(rev0);
        float pr_, pi_;
        __sincosf(rev0 * TWOPI, &pi_, &pr_);
        float revs = grow ? (wi * INV2PI * (float)CC) : 0.0f;
        revs -= floorf(revs);
        float spr, spi;
        __sincosf(revs * TWOPI, &spi, &spr);
        float str = 0.0f, sti = 0.0f, btr = 1.0f, bti = 0.0f;
        float ar = ACCY[n * 66 + 0];
        float ai = ACCY[(64 + n) * 66 + 0];
        for (int c = 0; c < NCH; ++c) {
            int cn = (c < NCH-1) ? (c+1) : (NCH-1);
            float nar = ACCY[n * 66 + cn];
            float nai = ACCY[(64 + n) * 66 + cn];
            float gm = exp2f(fmaf(gmd, (float)c, gma));
            float gxr = gm * pr_, gxi = gm * pi_;
            float gr_ = gxr*str - gxi*sti;
            float gi_ = gxr*sti + gxi*str;
            GT[c*200 + n]      = (short)f2bf(gr_);
            GT[c*200 + 64 + n] = (short)f2bf(gi_);
            float t1r = alr*str - ali*sti + btr*ar - bti*ai;
            float t1i = alr*sti + ali*str + btr*ai + bti*ar;
            str = t1r; sti = t1i;
            float nbr = btr*tur - bti*tui;
            float nbi = btr*tui + bti*tur;
            btr = nbr; bti = nbi;
            float npr = pr_*spr - pi_*spi;
            float npi = pr_*spi + pi_*spr;
            pr_ = npr; pi_ = npi;
            ar = nar; ai = nai;
        }
    }

    __syncthreads();

    // ---- phase C: Y[64 t][64 c] = WC(64x192) * G(192x64) ----
    floatx4 yacc[4];
    #pragma unroll
    for (int nt = 0; nt < 4; ++nt) yacc[nt] = (floatx4){0.f,0.f,0.f,0.f};
    #pragma unroll
    for (int nt = 0; nt < 4; ++nt)
        #pragma unroll
        for (int ks = 0; ks < 6; ++ks) {
            short8 bfr = *(const short8*)&GT[(nt*16 + mrow)*200 + ks*32 + quad*8];
            yacc[nt] = __builtin_amdgcn_mfma_f32_16x16x32_bf16(cf[ks], bfr, yacc[nt], 0, 0, 0);
        }

    // Y to LDS (reuse ACCY, stride 67), then coalesced store
    #pragma unroll
    for (int nt = 0; nt < 4; ++nt)
        #pragma unroll
        for (int r = 0; r < 4; ++r) {
            int t = 16*wv + quad*4 + r;
            int c = nt*16 + mrow;
            ACCY[t * 67 + c] = yacc[nt][r];
        }

    __syncthreads();

    #pragma unroll
    for (int i = 0; i < 4; ++i) {
        int q = i * 256 + tid;
        int l = q * 4;
        int c = l >> 6, t0 = l & 63;
        float4 o;
        o.x = ACCY[(t0+0)*67 + c];
        o.y = ACCY[(t0+1)*67 + c];
        o.z = ACCY[(t0+2)*67 + c];
        o.w = ACCY[(t0+3)*67 + c];
        ((float4*)yb)[q] = o;
    }
}

extern "C" void kernel_launch(void* const* d_in, const int* in_sizes, int n_in,
                              void* d_out, int out_size, void* d_ws, size_t ws_size,
                              hipStream_t stream) {
    const float* u   = (const float*)d_in[0];
    const float* W   = (const float*)d_in[1];
    const float* D   = (const float*)d_in[2];
    const float* ls  = (const float*)d_in[3];
    const float* lre = (const float*)d_in[4];
    const float* lim = (const float*)d_in[5];
    float* y  = (float*)d_out;
    float* ws = (float*)d_ws;   // H*N*8*4 = 1 MiB

    dss_setup<<<(HH * NM + 255) / 256, 256, 0, stream>>>(W, ls, lre, lim, ws);
    dss_khead<<<HH, 64, 0, stream>>>(D, ws);
    dss_main<<<BB * HH, 256, 0, stream>>>(u, ws, y);
}